// Round 1
// 310.301 us; speedup vs baseline: 1.1000x; 1.1000x over previous
//
#include <hip/hip_runtime.h>
#include <hip/hip_bf16.h>

// Problem constants
#define Bsz 8192
#define Isz 1024
#define Hsz 1024
#define Ksz 2048   // I + H (concatenated GEMM K)
#define Nsz 4096   // 4*H  (stacked gates)

// GEMM tiling: 256x256 tile, BK=64, 8 waves (2M x 4N), 8-phase counted-vmcnt
#define BM 256
#define BN 256
#define BK 64
#define NT (Ksz / BK)   // 32 K-tiles

typedef __attribute__((ext_vector_type(8))) short bf16x8;  // 8 bf16 = 4 VGPRs
typedef __attribute__((ext_vector_type(4))) float f32x4;
typedef __attribute__((ext_vector_type(8))) unsigned short ushort8;

__device__ __forceinline__ void async_copy16(const void* g, void* l) {
  __builtin_amdgcn_global_load_lds(
      (const __attribute__((address_space(1))) void*)g,
      (__attribute__((address_space(3))) void*)l, 16, 0, 0);
}

__device__ __forceinline__ float sigmoid_f(float x) {
  return 1.0f / (1.0f + __expf(-x));
}
__device__ __forceinline__ float tanh_f(float x) {
  x = fminf(15.0f, fmaxf(-15.0f, x));   // avoid inf/inf -> NaN
  const float e = __expf(-2.0f * x);
  return (1.0f - e) / (1.0f + e);
}

// register-only f32 -> bf16 bits (no local-array puns -> no scratch)
__device__ __forceinline__ unsigned short bfc(float f) {
  return __builtin_bit_cast(unsigned short, __float2bfloat16(f));
}
__device__ __forceinline__ ushort8 cvt8v(float4 v0, float4 v1) {
  ushort8 o;
  o[0] = bfc(v0.x); o[1] = bfc(v0.y); o[2] = bfc(v0.z); o[3] = bfc(v0.w);
  o[4] = bfc(v1.x); o[5] = bfc(v1.y); o[6] = bfc(v1.z); o[7] = bfc(v1.w);
  return o;
}

// ---------------------------------------------------------------------------
// Prep: build bf16 A=[x|h] (8192x2048), gate-interleaved bf16 W' (4096x2048)
// with W'[4*hh+g][k] = (k<I ? Wx : Wh)[g*H+hh][k'], and bsum[4*hh+g]=bx+bh.
// (unchanged from previous round — known good; will surface in top-5 counters
//  once the GEMM drops below it, giving evidence for round 2)
// ---------------------------------------------------------------------------
__global__ __launch_bounds__(256) void prep_kernel(
    const float* __restrict__ x, const float* __restrict__ h,
    const float* __restrict__ Wx, const float* __restrict__ Wh,
    const float* __restrict__ bx, const float* __restrict__ bh,
    __hip_bfloat16* __restrict__ Abf, __hip_bfloat16* __restrict__ Wbf,
    float* __restrict__ bsum) {
  const int idx = blockIdx.x * 256 + threadIdx.x;
  const int ATH = (Bsz * Ksz) / 8;  // 2,097,152 threads for A
  if (idx < ATH) {
    const int b = idx >> 8;            // row (2048 elems = 256 chunks/row)
    const int k = (idx & 255) << 3;    // col
    const float* src = (k < Isz) ? (x + (size_t)b * Isz + k)
                                 : (h + (size_t)b * Hsz + (k - Isz));
    const float4 v0 = ((const float4*)src)[0];
    const float4 v1 = ((const float4*)src)[1];
    *(ushort8*)(Abf + (size_t)b * Ksz + k) = cvt8v(v0, v1);
  } else {
    const int t2 = idx - ATH;          // 1,048,576 threads for W'
    const int r = t2 >> 8;             // permuted row 4*hh+g
    const int k = (t2 & 255) << 3;
    const int hh = r >> 2, g = r & 3;
    const float* src = (k < Isz) ? (Wx + (size_t)(g * Hsz + hh) * Isz + k)
                                 : (Wh + (size_t)(g * Hsz + hh) * Hsz + (k - Isz));
    const float4 v0 = ((const float4*)src)[0];
    const float4 v1 = ((const float4*)src)[1];
    *(ushort8*)(Wbf + (size_t)r * Ksz + k) = cvt8v(v0, v1);
  }
  if (idx < Nsz) {
    const int hh = idx >> 2, g = idx & 3;
    bsum[idx] = bx[g * Hsz + hh] + bh[g * Hsz + hh];
  }
}

// ---------------------------------------------------------------------------
// GEMM (A·W'^T) + fused LSTM epilogue — 256² / 8-phase / counted-vmcnt.
//
// 512 threads = 8 waves (wm in {0,1} x wn in {0..3}); per-wave C = 128x64
// (acc[8][4] f32x4 = 128 VGPR). LDS = 2 dbuf x (256x64) x {A,B} x bf16
// = 128 KB -> 1 block/CU, 2 waves/SIMD.
//
// LDS XOR swizzle (same as verified 128² version): row = 128 B = 8 qwords;
// qword j of row r stored at slot j ^ (r&7); achieved by pre-swizzling the
// per-lane GLOBAL source address (global_load_lds dest must stay linear,
// rule #21), unswizzled on ds_read via ((ks*4+q) ^ (cl&7)).
//
// 8-phase schedule per K-tile t (buffer c = t&1), 4 phases of:
//   { ds_reads ; 1 half-tile global_load_lds ; barrier ; 16 MFMA ; barrier }
// ds_reads: ph0 = all B (8) + A m0,m1 (4) = 12; ph1..3 = 4 A each.
// Slot-death proof for the staging targets:
//   ph0/ph1 stage (t+1).A0/A1 -> buf[c^1].A : that buffer was last read in
//     tile t-1, which completed before tile t began              -> safe.
//   ph2/ph3 stage (t+2).B0/B1 -> buf[c].B   : ALL B reads of tile t happen
//     in ph0 and complete before ph0's MFMA (auto lgkmcnt), hence before
//     ph0's end barrier; stages issue after ph1's end barrier    -> safe.
// End-of-tile: s_waitcnt vmcnt(4) (NOT 0) -> tile t+1 fully landed, the 4
// loads of (t+2).B stay in flight across the barrier (T4). Peeled tail:
// t=NT-2 issues only (NT-1).A and drains with vmcnt(0); t=NT-1 stages none.
// ---------------------------------------------------------------------------
__global__ __launch_bounds__(512, 2) void lstm_gemm_kernel(
    const __hip_bfloat16* __restrict__ A,   // [8192][2048]
    const __hip_bfloat16* __restrict__ W,   // [4096][2048] gate-interleaved
    const float* __restrict__ bsum,         // [4096] gate-interleaved
    const float* __restrict__ c_prev,       // [8192][1024]
    float* __restrict__ c_out,              // [8192][1024]
    float* __restrict__ h_out) {            // [8192][1024]
  __shared__ ulong2 smem_raw[8192];         // 128 KB
  __hip_bfloat16* const As = (__hip_bfloat16*)smem_raw;     // bufs at 0,32 KB
  __hip_bfloat16* const Bs = As + 2 * BM * BK;              // bufs at 64,96 KB
  char* const smemc = (char*)smem_raw;

  const int tid = threadIdx.x;
  const int lane = tid & 63;
  const int wave = tid >> 6;     // 0..7
  const int wm = wave >> 2;      // 0..1 : 128-row half of the 256-row tile
  const int wn = wave & 3;       // 0..3 : 64-col strip of the 256-col tile

  // T1: bijective XCD swizzle (512 blocks, 512 % 8 == 0). Per-XCD chunk of 64
  // blocks = 2 col-tiles x all 32 row-tiles -> 2 MB of B resident per L2.
  const int orig = blockIdx.x;
  const int swz = (orig & 7) * 64 + (orig >> 3);
  const int bx = swz & 31;       // 32 row tiles
  const int by = swz >> 5;       // 16 col tiles
  const int row0 = bx * BM;
  const int col0 = by * BN;

  const __hip_bfloat16* const Ag = A + (size_t)row0 * Ksz;
  const __hip_bfloat16* const Wg = W + (size_t)col0 * Ksz;

  // staging: half-tile = 128 rows x 64 cols = 1024 x 16 B chunks; thread
  // stages chunks tid and tid+512. Row part: sr, sr+64 (64 == 0 mod 8 so the
  // swizzled column offset `so` is identical for both chunks).
  const int sr = tid >> 3;                       // 0..63
  const int so = ((tid & 7) ^ (sr & 7)) << 3;    // pre-swizzled elem offset

  auto stage = [&](const __hip_bfloat16* gsrc /* mat + halfrow0*Ksz + kt + so */,
                   char* lhalf /* 16 KB half base */) {
#pragma unroll
    for (int p = 0; p < 2; ++p)
      async_copy16(gsrc + (size_t)(sr + p * 64) * Ksz,
                   lhalf + (tid + p * 512) * 16);
  };

  const int q = lane >> 4;    // quad
  const int cl = lane & 15;   // row-in-16 within a fragment
  const int phi = cl & 7;     // read-side swizzle phase
  const int swz0 = ((0 + q) ^ phi) << 3;   // ks=0 qword slot -> elem offset
  const int swz1 = ((4 + q) ^ phi) << 3;   // ks=1
  const int aoff0 = (wm * 128 + cl) * BK + swz0;
  const int aoff1 = (wm * 128 + cl) * BK + swz1;
  const int boff0 = (wn * 64 + cl) * BK + swz0;
  const int boff1 = (wn * 64 + cl) * BK + swz1;

  // ---- prologue: tile0 {A0,A1,B0,B1} + tile1 {B0,B1}; leave tile1.B flying
  stage(Ag + so, smemc);
  stage(Ag + (size_t)128 * Ksz + so, smemc + 16384);
  stage(Wg + so, smemc + 65536);
  stage(Wg + (size_t)128 * Ksz + so, smemc + 65536 + 16384);
  __builtin_amdgcn_sched_barrier(0);   // pin issue order for vmcnt counting
  stage(Wg + BK + so, smemc + 65536 + 32768);
  stage(Wg + BK + (size_t)128 * Ksz + so, smemc + 65536 + 32768 + 16384);
  asm volatile("s_waitcnt vmcnt(4)" ::: "memory");  // tile0 landed
  __builtin_amdgcn_sched_barrier(0);
  __builtin_amdgcn_s_barrier();
  asm volatile("" ::: "memory");
  __builtin_amdgcn_sched_barrier(0);

  f32x4 acc[8][4] = {};

  for (int t = 0; t < NT; ++t) {
    const __hip_bfloat16* const Asb = As + (t & 1) * (BM * BK);
    const __hip_bfloat16* const Bsb = Bs + (t & 1) * (BM * BK);
    char* const nA = smemc + (((t + 1) & 1) * 32768);          // (t+1).A dest
    char* const nB = smemc + 65536 + ((t & 1) * 32768);        // (t+2).B dest
    const int kA = (t + 1) * BK;
    const int kB = (t + 2) * BK;
    const bool doA = (t + 1) < NT;   // uniform
    const bool doB = (t + 2) < NT;   // uniform

    bf16x8 bfr[4][2];   // B front-loaded in ph0, lives across the tile

#pragma unroll
    for (int ph = 0; ph < 4; ++ph) {
      const int m0 = 2 * ph;
      // ds_reads for this phase's two A fragments (both ks halves)
      bf16x8 a00 = *(const bf16x8*)(Asb + aoff0 + m0 * (16 * BK));
      bf16x8 a01 = *(const bf16x8*)(Asb + aoff1 + m0 * (16 * BK));
      bf16x8 a10 = *(const bf16x8*)(Asb + aoff0 + (m0 + 1) * (16 * BK));
      bf16x8 a11 = *(const bf16x8*)(Asb + aoff1 + (m0 + 1) * (16 * BK));
      if (ph == 0) {
#pragma unroll
        for (int n = 0; n < 4; ++n) {
          bfr[n][0] = *(const bf16x8*)(Bsb + boff0 + n * (16 * BK));
          bfr[n][1] = *(const bf16x8*)(Bsb + boff1 + n * (16 * BK));
        }
      }
      // one half-tile of prefetch per phase (2 x global_load_lds)
      if (ph == 0 && doA) stage(Ag + kA + so, nA);
      if (ph == 1 && doA) stage(Ag + kA + (size_t)128 * Ksz + so, nA + 16384);
      if (ph == 2 && doB) stage(Wg + kB + so, nB);
      if (ph == 3 && doB) stage(Wg + kB + (size_t)128 * Ksz + so, nB + 16384);

      __builtin_amdgcn_sched_barrier(0);
      __builtin_amdgcn_s_barrier();
      asm volatile("" ::: "memory");
      __builtin_amdgcn_sched_barrier(0);

      __builtin_amdgcn_s_setprio(1);
#pragma unroll
      for (int n = 0; n < 4; ++n) {
        acc[m0][n]     = __builtin_amdgcn_mfma_f32_16x16x32_bf16(a00, bfr[n][0], acc[m0][n], 0, 0, 0);
        acc[m0][n]     = __builtin_amdgcn_mfma_f32_16x16x32_bf16(a01, bfr[n][1], acc[m0][n], 0, 0, 0);
        acc[m0 + 1][n] = __builtin_amdgcn_mfma_f32_16x16x32_bf16(a10, bfr[n][0], acc[m0 + 1][n], 0, 0, 0);
        acc[m0 + 1][n] = __builtin_amdgcn_mfma_f32_16x16x32_bf16(a11, bfr[n][1], acc[m0 + 1][n], 0, 0, 0);
      }
      __builtin_amdgcn_s_setprio(0);
      __builtin_amdgcn_sched_barrier(0);
      if (ph == 3) {
        if (t < NT - 2) {
          asm volatile("s_waitcnt vmcnt(4)" ::: "memory");   // counted, not 0
        } else if (t == NT - 2) {
          asm volatile("s_waitcnt vmcnt(0)" ::: "memory");   // drain for tail
        }
      }
      __builtin_amdgcn_s_barrier();
      asm volatile("" ::: "memory");
      __builtin_amdgcn_sched_barrier(0);
    }
  }

  // ---- fused LSTM epilogue (LDS round-trip in the now-dead buffer space) ----
  __syncthreads();
  float* const E = (float*)smem_raw + wave * (16 * 68);   // 8 x 4352 B = 34 KB

  float bj[4];
#pragma unroll
  for (int n = 0; n < 4; ++n)
    bj[n] = bsum[col0 + wn * 64 + n * 16 + cl];

  const int hw = (col0 >> 2) + wn * 16;  // wave's h-window start (16 h values)
  const int r16 = lane >> 2;             // read-phase row 0..15
  const int tt = lane & 3;               // read-phase h-quad 0..3

#pragma unroll
  for (int i = 0; i < 8; ++i) {
    // write phase: lane (q,cl) reg r holds C[q*4+r][n*16+cl] of this 16-row tile
#pragma unroll
    for (int n = 0; n < 4; ++n)
#pragma unroll
      for (int r = 0; r < 4; ++r)
        E[(q * 4 + r) * 68 + n * 16 + cl] = acc[i][n][r] + bj[n];
    __builtin_amdgcn_wave_barrier();  // keep write->read order (wave-private)
    // read phase: lane owns row r16, h = hw + tt*4 + (0..3); gate cols 4h'+g
    const float* Er = E + r16 * 68 + tt * 16;
    const float4 f0 = ((const float4*)Er)[0];  // gates of h+0
    const float4 f1 = ((const float4*)Er)[1];  // gates of h+1
    const float4 f2 = ((const float4*)Er)[2];  // gates of h+2
    const float4 f3 = ((const float4*)Er)[3];  // gates of h+3

    const int row = row0 + wm * 128 + i * 16 + r16;
    const size_t off = (size_t)row * Hsz + hw + tt * 4;
    const float4 cp4 = *(const float4*)(c_prev + off);
    float4 c4, h4;
    {
      const float cn = sigmoid_f(f0.y) * cp4.x + sigmoid_f(f0.x) * tanh_f(f0.w);
      c4.x = cn; h4.x = sigmoid_f(f0.z) * tanh_f(cn);
    }
    {
      const float cn = sigmoid_f(f1.y) * cp4.y + sigmoid_f(f1.x) * tanh_f(f1.w);
      c4.y = cn; h4.y = sigmoid_f(f1.z) * tanh_f(cn);
    }
    {
      const float cn = sigmoid_f(f2.y) * cp4.z + sigmoid_f(f2.x) * tanh_f(f2.w);
      c4.z = cn; h4.z = sigmoid_f(f2.z) * tanh_f(cn);
    }
    {
      const float cn = sigmoid_f(f3.y) * cp4.w + sigmoid_f(f3.x) * tanh_f(f3.w);
      c4.w = cn; h4.w = sigmoid_f(f3.z) * tanh_f(cn);
    }
    *(float4*)(c_out + off) = c4;
    *(float4*)(h_out + off) = h4;
    __builtin_amdgcn_wave_barrier();  // next i reuses E
  }
}

extern "C" void kernel_launch(void* const* d_in, const int* in_sizes, int n_in,
                              void* d_out, int out_size, void* d_ws,
                              size_t ws_size, hipStream_t stream) {
  (void)in_sizes; (void)n_in; (void)out_size; (void)ws_size;
  const float* x  = (const float*)d_in[0];
  const float* cp = (const float*)d_in[1];
  const float* hp = (const float*)d_in[2];
  const float* Wx = (const float*)d_in[3];
  const float* bx = (const float*)d_in[4];
  const float* Wh = (const float*)d_in[5];
  const float* bh = (const float*)d_in[6];

  __hip_bfloat16* Abf = (__hip_bfloat16*)d_ws;            // 32 MB
  __hip_bfloat16* Wbf = Abf + (size_t)Bsz * Ksz;          // 16 MB
  float* bsum = (float*)(Wbf + (size_t)Nsz * Ksz);        // 16 KB

  float* c_out = (float*)d_out;
  float* h_out = c_out + (size_t)Bsz * Hsz;

  const int total_threads = (Bsz * Ksz) / 8 + (Nsz * Ksz) / 8;  // 3,145,728
  prep_kernel<<<total_threads / 256, 256, 0, stream>>>(x, hp, Wx, Wh, bx, bh,
                                                       Abf, Wbf, bsum);
  dim3 grid(Bsz / BM * (Nsz / BN));  // 32 x 16 = 512 blocks (1D, swizzled)
  lstm_gemm_kernel<<<grid, 512, 0, stream>>>(Abf, Wbf, bsum, cp, c_out, h_out);
}

// Round 2
// 294.545 us; speedup vs baseline: 1.1589x; 1.0535x over previous
//
#include <hip/hip_runtime.h>
#include <hip/hip_bf16.h>

// Problem constants
#define Bsz 8192
#define Isz 1024
#define Hsz 1024
#define Ksz 2048   // I + H (concatenated GEMM K)
#define Nsz 4096   // 4*H  (stacked gates)

// GEMM tiling: 256x256 tile, BK=64, 8 waves (2M x 4N)
#define BM 256
#define BN 256
#define BK 64
#define NT (Ksz / BK)   // 32 K-tiles

typedef __attribute__((ext_vector_type(8))) short bf16x8;  // 8 bf16 = 4 VGPRs
typedef __attribute__((ext_vector_type(4))) float f32x4;
typedef __attribute__((ext_vector_type(8))) unsigned short ushort8;

__device__ __forceinline__ void async_copy16(const void* g, void* l) {
  __builtin_amdgcn_global_load_lds(
      (const __attribute__((address_space(1))) void*)g,
      (__attribute__((address_space(3))) void*)l, 16, 0, 0);
}

__device__ __forceinline__ float fast_rcp(float x) {
  return __builtin_amdgcn_rcpf(x);   // v_rcp_f32, ~1ulp; tolerance is 3e-2
}
__device__ __forceinline__ float sigmoid_f(float x) {
  return fast_rcp(1.0f + __expf(-x));
}
__device__ __forceinline__ float tanh_f(float x) {
  x = fminf(15.0f, fmaxf(-15.0f, x));   // avoid inf/inf -> NaN
  const float e = __expf(-2.0f * x);
  return (1.0f - e) * fast_rcp(1.0f + e);
}

// register-only f32 -> bf16 bits (no local-array puns -> no scratch)
__device__ __forceinline__ unsigned short bfc(float f) {
  return __builtin_bit_cast(unsigned short, __float2bfloat16(f));
}
__device__ __forceinline__ ushort8 cvt8v(float4 v0, float4 v1) {
  ushort8 o;
  o[0] = bfc(v0.x); o[1] = bfc(v0.y); o[2] = bfc(v0.z); o[3] = bfc(v0.w);
  o[4] = bfc(v1.x); o[5] = bfc(v1.y); o[6] = bfc(v1.z); o[7] = bfc(v1.w);
  return o;
}

// ---------------------------------------------------------------------------
// Prep: build bf16 A=[x|h] (8192x2048), gate-interleaved bf16 W' (4096x2048),
// bsum[4*hh+g]=bx+bh. Unchanged (coalesced, ~144 MB of traffic -> ~25-30 us
// expected; if it shows up in top-5 next profile, it becomes the target).
// ---------------------------------------------------------------------------
__global__ __launch_bounds__(256) void prep_kernel(
    const float* __restrict__ x, const float* __restrict__ h,
    const float* __restrict__ Wx, const float* __restrict__ Wh,
    const float* __restrict__ bx, const float* __restrict__ bh,
    __hip_bfloat16* __restrict__ Abf, __hip_bfloat16* __restrict__ Wbf,
    float* __restrict__ bsum) {
  const int idx = blockIdx.x * 256 + threadIdx.x;
  const int ATH = (Bsz * Ksz) / 8;  // 2,097,152 threads for A
  if (idx < ATH) {
    const int b = idx >> 8;            // row (2048 elems = 256 chunks/row)
    const int k = (idx & 255) << 3;    // col
    const float* src = (k < Isz) ? (x + (size_t)b * Isz + k)
                                 : (h + (size_t)b * Hsz + (k - Isz));
    const float4 v0 = ((const float4*)src)[0];
    const float4 v1 = ((const float4*)src)[1];
    *(ushort8*)(Abf + (size_t)b * Ksz + k) = cvt8v(v0, v1);
  } else {
    const int t2 = idx - ATH;          // 1,048,576 threads for W'
    const int r = t2 >> 8;             // permuted row 4*hh+g
    const int k = (t2 & 255) << 3;
    const int hh = r >> 2, g = r & 3;
    const float* src = (k < Isz) ? (Wx + (size_t)(g * Hsz + hh) * Isz + k)
                                 : (Wh + (size_t)(g * Hsz + hh) * Hsz + (k - Isz));
    const float4 v0 = ((const float4*)src)[0];
    const float4 v1 = ((const float4*)src)[1];
    *(ushort8*)(Wbf + (size_t)r * Ksz + k) = cvt8v(v0, v1);
  }
  if (idx < Nsz) {
    const int hh = idx >> 2, g = idx & 3;
    bsum[idx] = bx[g * Hsz + hh] + bh[g * Hsz + hh];
  }
}

// ---------------------------------------------------------------------------
// GEMM (A·W'^T) + fused LSTM epilogue — 256², software-pipelined ds_reads,
// 2 barriers per K-tile (was 8), counted vmcnt.
//
// Round-1 post-mortem: 8 barriers/tile + per-phase fenced ds_reads left ~820
// idle cyc/phase (MfmaUtil 38.7%). This version:
//   - A-fragment ds_reads issue ONE PHASE EARLY (ping-pong aE/aO reg pairs),
//     hiding LDS latency under the previous MFMA cluster.
//   - Only the per-tile R0 burst (8 B + 2 A reads) is exposed, once per tile.
//   - Barriers/tile: entry (after vmcnt) + one mid barrier. Proofs:
//     H1 (B overwrite): B(t) reads complete before each wave's ph0 MFMA
//        (register dep), which precedes the mid barrier; B(t+2) stages issue
//        after the mid barrier -> safe.
//     H2 (A overwrite): A(t+1) targets buf[(t+1)&1], last read in tile t-1;
//        all waves passed the entry barrier of t after those reads -> safe.
//     H3 (buffer validity): per-wave vmcnt(4) + entry barrier -> all waves'
//        A(t+1)/B(t+1) stages landed before tile t+1 reads them.
//   - VMEM issue order pinned with sched_barrier(0) after each stage pair
//     (vmcnt(4) counting depends on program order): per tile
//     A0(t+1),A1(t+1),B0(t+2),B1(t+2); vmcnt(4) leaves exactly B(t+2) flying.
//
// LDS XOR swizzle unchanged: qword j of row r at slot j^(r&7), via
// pre-swizzled GLOBAL source (global_load_lds dest stays linear, rule #21),
// unswizzled on ds_read via ((ks*4+q) ^ (cl&7)). Bank conflicts measured 0.
// ---------------------------------------------------------------------------
__global__ __launch_bounds__(512, 2) void lstm_gemm_kernel(
    const __hip_bfloat16* __restrict__ A,   // [8192][2048]
    const __hip_bfloat16* __restrict__ W,   // [4096][2048] gate-interleaved
    const float* __restrict__ bsum,         // [4096] gate-interleaved
    const float* __restrict__ c_prev,       // [8192][1024]
    float* __restrict__ c_out,              // [8192][1024]
    float* __restrict__ h_out) {            // [8192][1024]
  __shared__ ulong2 smem_raw[8192];         // 128 KB
  __hip_bfloat16* const As = (__hip_bfloat16*)smem_raw;     // bufs at 0,32 KB
  __hip_bfloat16* const Bs = As + 2 * BM * BK;              // bufs at 64,96 KB
  char* const smemc = (char*)smem_raw;

  const int tid = threadIdx.x;
  const int lane = tid & 63;
  const int wave = tid >> 6;     // 0..7
  const int wm = wave >> 2;      // 0..1 : 128-row half of the 256-row tile
  const int wn = wave & 3;       // 0..3 : 64-col strip of the 256-col tile

  // T1: bijective XCD swizzle (512 blocks, 512 % 8 == 0).
  const int orig = blockIdx.x;
  const int swz = (orig & 7) * 64 + (orig >> 3);
  const int bx = swz & 31;       // 32 row tiles
  const int by = swz >> 5;       // 16 col tiles
  const int row0 = bx * BM;
  const int col0 = by * BN;

  const __hip_bfloat16* const Ag = A + (size_t)row0 * Ksz;
  const __hip_bfloat16* const Wg = W + (size_t)col0 * Ksz;

  // staging: half-tile = 128 rows x 64 cols = 1024 x 16 B chunks; thread
  // stages chunks tid and tid+512 (row sr, sr+64; 64%8==0 so same swizzle).
  const int sr = tid >> 3;                       // 0..63
  const int so = ((tid & 7) ^ (sr & 7)) << 3;    // pre-swizzled elem offset

  auto stage = [&](const __hip_bfloat16* gsrc, char* lhalf) {
#pragma unroll
    for (int p = 0; p < 2; ++p)
      async_copy16(gsrc + (size_t)(sr + p * 64) * Ksz,
                   lhalf + (tid + p * 512) * 16);
  };

  const int q = lane >> 4;    // quad
  const int cl = lane & 15;   // row-in-16 within a fragment
  const int phi = cl & 7;     // read-side swizzle phase
  const int swz0 = ((0 + q) ^ phi) << 3;   // ks=0 qword slot -> elem offset
  const int swz1 = ((4 + q) ^ phi) << 3;   // ks=1
  const int aoff0 = (wm * 128 + cl) * BK + swz0;
  const int aoff1 = (wm * 128 + cl) * BK + swz1;
  const int boff0 = (wn * 64 + cl) * BK + swz0;
  const int boff1 = (wn * 64 + cl) * BK + swz1;

  // ---- prologue: tile0 {A0,A1,B0,B1} + tile1 {B0,B1}; leave tile1.B flying
  stage(Ag + so, smemc);
  stage(Ag + (size_t)128 * Ksz + so, smemc + 16384);
  stage(Wg + so, smemc + 65536);
  stage(Wg + (size_t)128 * Ksz + so, smemc + 65536 + 16384);
  __builtin_amdgcn_sched_barrier(0);   // pin issue order for vmcnt counting
  stage(Wg + BK + so, smemc + 65536 + 32768);
  stage(Wg + BK + (size_t)128 * Ksz + so, smemc + 65536 + 32768 + 16384);
  __builtin_amdgcn_sched_barrier(0);
  asm volatile("s_waitcnt vmcnt(4)" ::: "memory");  // tile0 landed
  __builtin_amdgcn_s_barrier();
  __builtin_amdgcn_sched_barrier(0);

  f32x4 acc[8][4] = {};

// read one A fragment pair (rows m, m+1 of this wave's 8) into dst[2][2]
#define LDA(dst, m)                                                        \
  dst[0][0] = *(const bf16x8*)(Asb + aoff0 + (m) * (16 * BK));             \
  dst[0][1] = *(const bf16x8*)(Asb + aoff1 + (m) * (16 * BK));             \
  dst[1][0] = *(const bf16x8*)(Asb + aoff0 + ((m) + 1) * (16 * BK));       \
  dst[1][1] = *(const bf16x8*)(Asb + aoff1 + ((m) + 1) * (16 * BK));

// MFMA cluster: rows mi,mi+1 x all 4 n x both ks, operands p, setprio-wrapped
#define CLUSTER(mi, p)                                                     \
  __builtin_amdgcn_s_setprio(1);                                           \
  _Pragma("unroll")                                                        \
  for (int n = 0; n < 4; ++n) {                                            \
    acc[mi][n] = __builtin_amdgcn_mfma_f32_16x16x32_bf16(                  \
        p[0][0], b0[n][0], acc[mi][n], 0, 0, 0);                           \
    acc[mi][n] = __builtin_amdgcn_mfma_f32_16x16x32_bf16(                  \
        p[0][1], b0[n][1], acc[mi][n], 0, 0, 0);                           \
    acc[(mi) + 1][n] = __builtin_amdgcn_mfma_f32_16x16x32_bf16(            \
        p[1][0], b0[n][0], acc[(mi) + 1][n], 0, 0, 0);                     \
    acc[(mi) + 1][n] = __builtin_amdgcn_mfma_f32_16x16x32_bf16(            \
        p[1][1], b0[n][1], acc[(mi) + 1][n], 0, 0, 0);                     \
  }                                                                        \
  __builtin_amdgcn_s_setprio(0);

  for (int t = 0; t < NT; ++t) {
    const __hip_bfloat16* const Asb = As + (t & 1) * (BM * BK);
    const __hip_bfloat16* const Bsb = Bs + (t & 1) * (BM * BK);
    char* const nA = smemc + (((t + 1) & 1) * 32768);          // (t+1).A dest
    char* const nB = smemc + 65536 + ((t & 1) * 32768);        // (t+2).B dest
    const int kA = (t + 1) * BK;
    const int kB = (t + 2) * BK;
    const bool doA = (t + 1) < NT;   // uniform
    const bool doB = (t + 2) < NT;   // uniform

    bf16x8 b0[4][2];       // all B frags, read in R0, live across the tile
    bf16x8 aE[2][2], aO[2][2];  // ping-pong A fragment pairs

    // R0 (exposed once per tile): all B + A[0,1]
#pragma unroll
    for (int n = 0; n < 4; ++n) {
      b0[n][0] = *(const bf16x8*)(Bsb + boff0 + n * (16 * BK));
      b0[n][1] = *(const bf16x8*)(Bsb + boff1 + n * (16 * BK));
    }
    LDA(aE, 0)

    // ph0: prefetch A[2,3]; stage A(t+1) half0; MFMA m0,m1
    LDA(aO, 2)
    if (doA) stage(Ag + kA + so, nA);
    __builtin_amdgcn_sched_barrier(0);
    CLUSTER(0, aE)

    // ph1: prefetch A[4,5]; stage A(t+1) half1; MFMA m2,m3
    LDA(aE, 4)
    if (doA) stage(Ag + kA + (size_t)128 * Ksz + so, nA + 16384);
    __builtin_amdgcn_sched_barrier(0);
    CLUSTER(2, aO)

    // mid barrier: all waves' B(t) reads are done (consumed by their ph0
    // MFMA) -> B(t+2) staging below may overwrite that LDS region.
    __builtin_amdgcn_s_barrier();
    __builtin_amdgcn_sched_barrier(0);

    // ph2: prefetch A[6,7]; stage B(t+2) half0; MFMA m4,m5
    LDA(aO, 6)
    if (doB) stage(Wg + kB + so, nB);
    __builtin_amdgcn_sched_barrier(0);
    CLUSTER(4, aE)

    // ph3: stage B(t+2) half1; MFMA m6,m7
    if (doB) stage(Wg + kB + (size_t)128 * Ksz + so, nB + 16384);
    __builtin_amdgcn_sched_barrier(0);
    CLUSTER(6, aO)

    // end-of-tile: counted drain (A(t+1),B(t+1) landed; B(t+2) stays flying)
    if (t < NT - 2) {
      asm volatile("s_waitcnt vmcnt(4)" ::: "memory");
    } else if (t == NT - 2) {
      asm volatile("s_waitcnt vmcnt(0)" ::: "memory");   // drain for tail
    }
    __builtin_amdgcn_s_barrier();
    __builtin_amdgcn_sched_barrier(0);
  }
#undef LDA
#undef CLUSTER

  // ---- fused LSTM epilogue (LDS round-trip in the now-dead buffer space) ----
  __syncthreads();
  float* const E = (float*)smem_raw + wave * (16 * 68);   // 8 x 4352 B = 34 KB

  float bj[4];
#pragma unroll
  for (int n = 0; n < 4; ++n)
    bj[n] = bsum[col0 + wn * 64 + n * 16 + cl];

  const int hw = (col0 >> 2) + wn * 16;  // wave's h-window start (16 h values)
  const int r16 = lane >> 2;             // read-phase row 0..15
  const int tt = lane & 3;               // read-phase h-quad 0..3

#pragma unroll
  for (int i = 0; i < 8; ++i) {
    // write phase: lane (q,cl) reg r holds C[q*4+r][n*16+cl] of this 16-row tile
#pragma unroll
    for (int n = 0; n < 4; ++n)
#pragma unroll
      for (int r = 0; r < 4; ++r)
        E[(q * 4 + r) * 68 + n * 16 + cl] = acc[i][n][r] + bj[n];
    __builtin_amdgcn_wave_barrier();  // keep write->read order (wave-private)
    // read phase: lane owns row r16, h = hw + tt*4 + (0..3); gate cols 4h'+g
    const float* Er = E + r16 * 68 + tt * 16;
    const float4 f0 = ((const float4*)Er)[0];  // gates of h+0
    const float4 f1 = ((const float4*)Er)[1];  // gates of h+1
    const float4 f2 = ((const float4*)Er)[2];  // gates of h+2
    const float4 f3 = ((const float4*)Er)[3];  // gates of h+3

    const int row = row0 + wm * 128 + i * 16 + r16;
    const size_t off = (size_t)row * Hsz + hw + tt * 4;
    const float4 cp4 = *(const float4*)(c_prev + off);
    float4 c4, h4;
    {
      const float cn = sigmoid_f(f0.y) * cp4.x + sigmoid_f(f0.x) * tanh_f(f0.w);
      c4.x = cn; h4.x = sigmoid_f(f0.z) * tanh_f(cn);
    }
    {
      const float cn = sigmoid_f(f1.y) * cp4.y + sigmoid_f(f1.x) * tanh_f(f1.w);
      c4.y = cn; h4.y = sigmoid_f(f1.z) * tanh_f(cn);
    }
    {
      const float cn = sigmoid_f(f2.y) * cp4.z + sigmoid_f(f2.x) * tanh_f(f2.w);
      c4.z = cn; h4.z = sigmoid_f(f2.z) * tanh_f(cn);
    }
    {
      const float cn = sigmoid_f(f3.y) * cp4.w + sigmoid_f(f3.x) * tanh_f(f3.w);
      c4.w = cn; h4.w = sigmoid_f(f3.z) * tanh_f(cn);
    }
    *(float4*)(c_out + off) = c4;
    *(float4*)(h_out + off) = h4;
    __builtin_amdgcn_wave_barrier();  // next i reuses E
  }
}

extern "C" void kernel_launch(void* const* d_in, const int* in_sizes, int n_in,
                              void* d_out, int out_size, void* d_ws,
                              size_t ws_size, hipStream_t stream) {
  (void)in_sizes; (void)n_in; (void)out_size; (void)ws_size;
  const float* x  = (const float*)d_in[0];
  const float* cp = (const float*)d_in[1];
  const float* hp = (const float*)d_in[2];
  const float* Wx = (const float*)d_in[3];
  const float* bx = (const float*)d_in[4];
  const float* Wh = (const float*)d_in[5];
  const float* bh = (const float*)d_in[6];

  __hip_bfloat16* Abf = (__hip_bfloat16*)d_ws;            // 32 MB
  __hip_bfloat16* Wbf = Abf + (size_t)Bsz * Ksz;          // 16 MB
  float* bsum = (float*)(Wbf + (size_t)Nsz * Ksz);        // 16 KB

  float* c_out = (float*)d_out;
  float* h_out = c_out + (size_t)Bsz * Hsz;

  const int total_threads = (Bsz * Ksz) / 8 + (Nsz * Ksz) / 8;  // 3,145,728
  prep_kernel<<<total_threads / 256, 256, 0, stream>>>(x, hp, Wx, Wh, bx, bh,
                                                       Abf, Wbf, bsum);
  dim3 grid(Bsz / BM * (Nsz / BN));  // 32 x 16 = 512 blocks (1D, swizzled)
  lstm_gemm_kernel<<<grid, 512, 0, stream>>>(Abf, Wbf, bsum, cp, c_out, h_out);
}

// Round 3
// 293.691 us; speedup vs baseline: 1.1622x; 1.0029x over previous
//
#include <hip/hip_runtime.h>
#include <hip/hip_bf16.h>

// Problem constants
#define Bsz 8192
#define Isz 1024
#define Hsz 1024
#define Ksz 2048   // I + H (concatenated GEMM K)
#define Nsz 4096   // 4*H  (stacked gates)

// GEMM tiling: 256x256 tile, BK=64, 8 waves (2M x 4N)
#define BM 256
#define BN 256
#define BK 64
#define NT (Ksz / BK)      // 32 K-tiles
#define BUF (BM * BK)      // 16384 bf16 elems = 32 KB per buffer

typedef __attribute__((ext_vector_type(8))) short bf16x8;  // 8 bf16 = 4 VGPRs
typedef __attribute__((ext_vector_type(4))) float f32x4;
typedef __attribute__((ext_vector_type(8))) unsigned short ushort8;

__device__ __forceinline__ void async_copy16(const void* g, void* l) {
  __builtin_amdgcn_global_load_lds(
      (const __attribute__((address_space(1))) void*)g,
      (__attribute__((address_space(3))) void*)l, 16, 0, 0);
}

__device__ __forceinline__ float fast_rcp(float x) {
  return __builtin_amdgcn_rcpf(x);   // v_rcp_f32, ~1ulp; tolerance is 3e-2
}
__device__ __forceinline__ float sigmoid_f(float x) {
  return fast_rcp(1.0f + __expf(-x));
}
__device__ __forceinline__ float tanh_f(float x) {
  x = fminf(15.0f, fmaxf(-15.0f, x));   // avoid inf/inf -> NaN
  const float e = __expf(-2.0f * x);
  return (1.0f - e) * fast_rcp(1.0f + e);
}

// register-only f32 -> bf16 bits (no local-array puns -> no scratch)
__device__ __forceinline__ unsigned short bfc(float f) {
  return __builtin_bit_cast(unsigned short, __float2bfloat16(f));
}
__device__ __forceinline__ ushort8 cvt8v(float4 v0, float4 v1) {
  ushort8 o;
  o[0] = bfc(v0.x); o[1] = bfc(v0.y); o[2] = bfc(v0.z); o[3] = bfc(v0.w);
  o[4] = bfc(v1.x); o[5] = bfc(v1.y); o[6] = bfc(v1.z); o[7] = bfc(v1.w);
  return o;
}

// ---------------------------------------------------------------------------
// Prep: build bf16 A=[x|h] (8192x2048), gate-interleaved bf16 W' (4096x2048),
// bsum[4*hh+g]=bx+bh. Unchanged.
// ---------------------------------------------------------------------------
__global__ __launch_bounds__(256) void prep_kernel(
    const float* __restrict__ x, const float* __restrict__ h,
    const float* __restrict__ Wx, const float* __restrict__ Wh,
    const float* __restrict__ bx, const float* __restrict__ bh,
    __hip_bfloat16* __restrict__ Abf, __hip_bfloat16* __restrict__ Wbf,
    float* __restrict__ bsum) {
  const int idx = blockIdx.x * 256 + threadIdx.x;
  const int ATH = (Bsz * Ksz) / 8;  // 2,097,152 threads for A
  if (idx < ATH) {
    const int b = idx >> 8;            // row (2048 elems = 256 chunks/row)
    const int k = (idx & 255) << 3;    // col
    const float* src = (k < Isz) ? (x + (size_t)b * Isz + k)
                                 : (h + (size_t)b * Hsz + (k - Isz));
    const float4 v0 = ((const float4*)src)[0];
    const float4 v1 = ((const float4*)src)[1];
    *(ushort8*)(Abf + (size_t)b * Ksz + k) = cvt8v(v0, v1);
  } else {
    const int t2 = idx - ATH;          // 1,048,576 threads for W'
    const int r = t2 >> 8;             // permuted row 4*hh+g
    const int k = (t2 & 255) << 3;
    const int hh = r >> 2, g = r & 3;
    const float* src = (k < Isz) ? (Wx + (size_t)(g * Hsz + hh) * Isz + k)
                                 : (Wh + (size_t)(g * Hsz + hh) * Hsz + (k - Isz));
    const float4 v0 = ((const float4*)src)[0];
    const float4 v1 = ((const float4*)src)[1];
    *(ushort8*)(Wbf + (size_t)r * Ksz + k) = cvt8v(v0, v1);
  }
  if (idx < Nsz) {
    const int hh = idx >> 2, g = idx & 3;
    bsum[idx] = bx[g * Hsz + hh] + bh[g * Hsz + hh];
  }
}

// ---------------------------------------------------------------------------
// GEMM (A·W'^T) + fused LSTM epilogue — 256², B triple-buffered (160 KB LDS),
// ONE barrier per K-tile, 8-MFMA clusters split by K-half.
//
// Round-2 post-mortem: true MFMA cost = 19.4 cyc/SIMD per 16x16x32 -> floor
// 2483 cyc/tile/SIMD; wall was ~4700. Stalls: R0 12-read burst, mid barrier,
// barrier skew. This version:
//   - B 3-buffer (As 2x32K @0, Bs 3x32K @64K = 160 KB exactly): B(t+2) stage
//     targets the buffer read in tile t-1 (dead since tile-t entry barrier)
//     -> MID BARRIER DELETED; one s_barrier per tile.
//   - Clusters of 8 MFMA (m-pair x 4n x ONE K-half). First MFMA of a tile
//     gates on 6 ds_reads (was 12); each cluster's operands issue one
//     cluster (~155-310 cyc) ahead, hiding LDS latency under pipe drain.
//   - vmcnt proof: per tile issue order A(t+1)h0,A(t+1)h1,B(t+2)h0,B(t+2)h1
//     (8 ops/thread, sched_barrier-pinned). End-of-tile vmcnt(4) leaves the
//     newest 4 (= B(t+2)) in flight; forces A(t+1),B(t+1) landed. Hence at
//     tile t: A(t) (issued t-1) and B(t) (issued t-2) are older than the
//     newest-4 at the end-of-(t-1) wait -> resident; entry barrier makes the
//     per-wave guarantee global. Tail: t=NT-2 drains vmcnt(0); NT-1 stages 0.
//   - Overwrite hazards: A(t+1) -> A buf (t+1)&1, last read t-1, dead.
//     B(t+2) -> B buf (t+2)%3 = buf read at t-1, dead.           Both safe.
//
// LDS XOR swizzle unchanged: qword j of row r at slot j^(r&7) via
// pre-swizzled GLOBAL source (dest linear, rule #21); read side ^(cl&7).
// ---------------------------------------------------------------------------
__global__ __launch_bounds__(512, 2) void lstm_gemm_kernel(
    const __hip_bfloat16* __restrict__ A,   // [8192][2048]
    const __hip_bfloat16* __restrict__ W,   // [4096][2048] gate-interleaved
    const float* __restrict__ bsum,         // [4096] gate-interleaved
    const float* __restrict__ c_prev,       // [8192][1024]
    float* __restrict__ c_out,              // [8192][1024]
    float* __restrict__ h_out) {            // [8192][1024]
  __shared__ ulong2 smem_raw[10240];        // 160 KB exactly
  __hip_bfloat16* const As = (__hip_bfloat16*)smem_raw;   // 2 bufs @ 0, 32 KB
  __hip_bfloat16* const Bs = As + 2 * BUF;                // 3 bufs @ 64 KB+

  const int tid = threadIdx.x;
  const int lane = tid & 63;
  const int wave = tid >> 6;     // 0..7
  const int wm = wave >> 2;      // 0..1 : 128-row half of the 256-row tile
  const int wn = wave & 3;       // 0..3 : 64-col strip of the 256-col tile

  // T1: bijective XCD swizzle (512 blocks, 512 % 8 == 0).
  const int orig = blockIdx.x;
  const int swz = (orig & 7) * 64 + (orig >> 3);
  const int bx = swz & 31;       // 32 row tiles
  const int by = swz >> 5;       // 16 col tiles
  const int row0 = bx * BM;
  const int col0 = by * BN;

  const __hip_bfloat16* const Ag = A + (size_t)row0 * Ksz;
  const __hip_bfloat16* const Wg = W + (size_t)col0 * Ksz;

  // staging: half-tile = 128 rows x 64 cols = 1024 x 16 B chunks; thread
  // stages chunks tid and tid+512 (rows sr, sr+64; 64%8==0 -> same swizzle).
  const int sr = tid >> 3;                       // 0..63
  const int so = ((tid & 7) ^ (sr & 7)) << 3;    // pre-swizzled elem offset

  auto stage = [&](const __hip_bfloat16* gsrc, char* lhalf) {
#pragma unroll
    for (int p = 0; p < 2; ++p)
      async_copy16(gsrc + (size_t)(sr + p * 64) * Ksz,
                   lhalf + (tid + p * 512) * 16);
  };

  const int q = lane >> 4;    // quad
  const int cl = lane & 15;   // row-in-16 within a fragment
  const int phi = cl & 7;     // read-side swizzle phase
  const int swz0 = ((0 + q) ^ phi) << 3;   // ks=0 qword slot -> elem offset
  const int swz1 = ((4 + q) ^ phi) << 3;   // ks=1
  const int aoff0 = (wm * 128 + cl) * BK + swz0;
  const int aoff1 = (wm * 128 + cl) * BK + swz1;
  const int boff0 = (wn * 64 + cl) * BK + swz0;
  const int boff1 = (wn * 64 + cl) * BK + swz1;

  // rotating B buffer pointers: read Bp0 (t%3), write Bp2 ((t+2)%3)
  const __hip_bfloat16* Bp0 = Bs;
  const __hip_bfloat16* Bp1 = Bs + BUF;
  const __hip_bfloat16* Bp2 = Bs + 2 * BUF;

  // ---- prologue: A(0) -> Abuf0; B(0) -> Bbuf0; B(1) -> Bbuf1 (B(1) may fly)
  stage(Ag + so, (char*)As);
  stage(Ag + (size_t)128 * Ksz + so, (char*)As + 16384);
  stage(Wg + so, (char*)Bs);
  stage(Wg + (size_t)128 * Ksz + so, (char*)Bs + 16384);
  __builtin_amdgcn_sched_barrier(0);   // pin VMEM order for vmcnt counting
  stage(Wg + BK + so, (char*)(Bs + BUF));
  stage(Wg + BK + (size_t)128 * Ksz + so, (char*)(Bs + BUF) + 16384);
  __builtin_amdgcn_sched_barrier(0);
  asm volatile("s_waitcnt vmcnt(4)" ::: "memory");  // A(0),B(0) landed
  __builtin_amdgcn_s_barrier();
  __builtin_amdgcn_sched_barrier(0);

  f32x4 acc[8][4] = {};

#define SB0 __builtin_amdgcn_sched_barrier(0);

// read A fragment pair (rows m, m+1), one K-half ks, into dst[0..1][ks]
#define LDA2(dst, m, ks)                                                   \
  dst[0][ks] = *(const bf16x8*)(Asb + aoff##ks + (m) * (16 * BK));         \
  dst[1][ks] = *(const bf16x8*)(Asb + aoff##ks + ((m) + 1) * (16 * BK));

// read all 4 B fragments of one K-half
#define LDB(ks)                                                            \
  _Pragma("unroll")                                                        \
  for (int n = 0; n < 4; ++n)                                              \
    b[n][ks] = *(const bf16x8*)(Bsb + boff##ks + n * (16 * BK));

// 8-MFMA cluster: rows mi,mi+1 x 4n x one K-half, setprio-wrapped
#define CL(mi, ks, p)                                                      \
  __builtin_amdgcn_s_setprio(1);                                           \
  _Pragma("unroll")                                                        \
  for (int n = 0; n < 4; ++n) {                                            \
    acc[mi][n] = __builtin_amdgcn_mfma_f32_16x16x32_bf16(                  \
        p[0][ks], b[n][ks], acc[mi][n], 0, 0, 0);                          \
    acc[(mi) + 1][n] = __builtin_amdgcn_mfma_f32_16x16x32_bf16(            \
        p[1][ks], b[n][ks], acc[(mi) + 1][n], 0, 0, 0);                    \
  }                                                                        \
  __builtin_amdgcn_s_setprio(0);                                           \
  __builtin_amdgcn_sched_barrier(0);

  for (int t = 0; t < NT; ++t) {
    const __hip_bfloat16* const Asb = As + (t & 1) * BUF;
    const __hip_bfloat16* const Bsb = Bp0;
    char* const nA = (char*)As + ((t + 1) & 1) * 32768;   // (t+1).A dest
    char* const nB = (char*)Bp2;                          // (t+2).B dest
    const int kA = (t + 1) * BK;
    const int kB = (t + 2) * BK;
    const bool doA = (t + 1) < NT;   // uniform
    const bool doB = (t + 2) < NT;   // uniform

    bf16x8 b[4][2];              // B fragments, both K-halves
    bf16x8 aE[2][2], aO[2][2];   // ping-pong A fragment pairs

    // R0 (exposed once per tile): 6 reads gate the first cluster
    LDB(0) LDA2(aE, 0, 0)
    if (doA) stage(Ag + kA + so, nA);
    SB0
    CL(0, 0, aE)

    LDB(1) LDA2(aE, 0, 1)
    if (doA) stage(Ag + kA + (size_t)128 * Ksz + so, nA + 16384);
    SB0
    CL(0, 1, aE)

    LDA2(aO, 2, 0)
    if (doB) stage(Wg + kB + so, nB);
    SB0
    CL(2, 0, aO)

    LDA2(aO, 2, 1)
    if (doB) stage(Wg + kB + (size_t)128 * Ksz + so, nB + 16384);
    SB0
    CL(2, 1, aO)

    LDA2(aE, 4, 0) SB0 CL(4, 0, aE)
    LDA2(aE, 4, 1) SB0 CL(4, 1, aE)
    LDA2(aO, 6, 0) SB0 CL(6, 0, aO)
    LDA2(aO, 6, 1) SB0 CL(6, 1, aO)

    // end-of-tile: counted drain; B(t+2) stays flying across the barrier
    if (t < NT - 2) {
      asm volatile("s_waitcnt vmcnt(4)" ::: "memory");
    } else if (t == NT - 2) {
      asm volatile("s_waitcnt vmcnt(0)" ::: "memory");   // drain for tail
    }
    __builtin_amdgcn_s_barrier();
    __builtin_amdgcn_sched_barrier(0);

    // rotate B buffers: new read = old Bp1; new write = old Bp0
    const __hip_bfloat16* const tmp = Bp0;
    Bp0 = Bp1; Bp1 = Bp2; Bp2 = tmp;
  }
#undef LDA2
#undef LDB
#undef CL
#undef SB0

  // ---- fused LSTM epilogue (LDS round-trip in the now-dead buffer space) ----
  __syncthreads();
  float* const E = (float*)smem_raw + wave * (16 * 68);   // 8 x 4352 B = 34 KB

  float bj[4];
#pragma unroll
  for (int n = 0; n < 4; ++n)
    bj[n] = bsum[col0 + wn * 64 + n * 16 + cl];

  const int hw = (col0 >> 2) + wn * 16;  // wave's h-window start (16 h values)
  const int r16 = lane >> 2;             // read-phase row 0..15
  const int tt = lane & 3;               // read-phase h-quad 0..3

#pragma unroll
  for (int i = 0; i < 8; ++i) {
    // write phase: lane (q,cl) reg r holds C[q*4+r][n*16+cl] of this 16-row tile
#pragma unroll
    for (int n = 0; n < 4; ++n)
#pragma unroll
      for (int r = 0; r < 4; ++r)
        E[(q * 4 + r) * 68 + n * 16 + cl] = acc[i][n][r] + bj[n];
    __builtin_amdgcn_wave_barrier();  // keep write->read order (wave-private)
    // read phase: lane owns row r16, h = hw + tt*4 + (0..3); gate cols 4h'+g
    const float* Er = E + r16 * 68 + tt * 16;
    const float4 f0 = ((const float4*)Er)[0];  // gates of h+0
    const float4 f1 = ((const float4*)Er)[1];  // gates of h+1
    const float4 f2 = ((const float4*)Er)[2];  // gates of h+2
    const float4 f3 = ((const float4*)Er)[3];  // gates of h+3

    const int row = row0 + wm * 128 + i * 16 + r16;
    const size_t off = (size_t)row * Hsz + hw + tt * 4;
    const float4 cp4 = *(const float4*)(c_prev + off);
    float4 c4, h4;
    {
      const float cn = sigmoid_f(f0.y) * cp4.x + sigmoid_f(f0.x) * tanh_f(f0.w);
      c4.x = cn; h4.x = sigmoid_f(f0.z) * tanh_f(cn);
    }
    {
      const float cn = sigmoid_f(f1.y) * cp4.y + sigmoid_f(f1.x) * tanh_f(f1.w);
      c4.y = cn; h4.y = sigmoid_f(f1.z) * tanh_f(cn);
    }
    {
      const float cn = sigmoid_f(f2.y) * cp4.z + sigmoid_f(f2.x) * tanh_f(f2.w);
      c4.z = cn; h4.z = sigmoid_f(f2.z) * tanh_f(cn);
    }
    {
      const float cn = sigmoid_f(f3.y) * cp4.w + sigmoid_f(f3.x) * tanh_f(f3.w);
      c4.w = cn; h4.w = sigmoid_f(f3.z) * tanh_f(cn);
    }
    *(float4*)(c_out + off) = c4;
    *(float4*)(h_out + off) = h4;
    __builtin_amdgcn_wave_barrier();  // next i reuses E
  }
}

extern "C" void kernel_launch(void* const* d_in, const int* in_sizes, int n_in,
                              void* d_out, int out_size, void* d_ws,
                              size_t ws_size, hipStream_t stream) {
  (void)in_sizes; (void)n_in; (void)out_size; (void)ws_size;
  const float* x  = (const float*)d_in[0];
  const float* cp = (const float*)d_in[1];
  const float* hp = (const float*)d_in[2];
  const float* Wx = (const float*)d_in[3];
  const float* bx = (const float*)d_in[4];
  const float* Wh = (const float*)d_in[5];
  const float* bh = (const float*)d_in[6];

  __hip_bfloat16* Abf = (__hip_bfloat16*)d_ws;            // 32 MB
  __hip_bfloat16* Wbf = Abf + (size_t)Bsz * Ksz;          // 16 MB
  float* bsum = (float*)(Wbf + (size_t)Nsz * Ksz);        // 16 KB

  float* c_out = (float*)d_out;
  float* h_out = c_out + (size_t)Bsz * Hsz;

  const int total_threads = (Bsz * Ksz) / 8 + (Nsz * Ksz) / 8;  // 3,145,728
  prep_kernel<<<total_threads / 256, 256, 0, stream>>>(x, hp, Wx, Wh, bx, bh,
                                                       Abf, Wbf, bsum);
  dim3 grid(Bsz / BM * (Nsz / BN));  // 32 x 16 = 512 blocks (1D, swizzled)
  lstm_gemm_kernel<<<grid, 512, 0, stream>>>(Abf, Wbf, bsum, cp, c_out, h_out);
}

// Round 4
// 285.677 us; speedup vs baseline: 1.1948x; 1.0281x over previous
//
#include <hip/hip_runtime.h>
#include <hip/hip_bf16.h>

// Problem constants
#define Bsz 8192
#define Isz 1024
#define Hsz 1024
#define Ksz 2048   // I + H (concatenated GEMM K)
#define Nsz 4096   // 4*H  (stacked gates)

// GEMM tiling: 256x256 tile, BK=64, 8 waves (2M x 4N)
#define BM 256
#define BN 256
#define BK 64
#define NT (Ksz / BK)      // 32 K-tiles
#define BUF (BM * BK)      // 16384 bf16 elems = 32 KB per buffer

typedef __attribute__((ext_vector_type(8))) short bf16x8;  // 8 bf16 = 4 VGPRs
typedef __attribute__((ext_vector_type(4))) float f32x4;
typedef __attribute__((ext_vector_type(8))) unsigned short ushort8;

__device__ __forceinline__ void async_copy16(const void* g, void* l) {
  __builtin_amdgcn_global_load_lds(
      (const __attribute__((address_space(1))) void*)g,
      (__attribute__((address_space(3))) void*)l, 16, 0, 0);
}

__device__ __forceinline__ float fast_rcp(float x) {
  return __builtin_amdgcn_rcpf(x);   // v_rcp_f32, ~1ulp; tolerance is 3e-2
}
__device__ __forceinline__ float sigmoid_f(float x) {
  return fast_rcp(1.0f + __expf(-x));
}
__device__ __forceinline__ float tanh_f(float x) {
  x = fminf(15.0f, fmaxf(-15.0f, x));   // avoid inf/inf -> NaN
  const float e = __expf(-2.0f * x);
  return (1.0f - e) * fast_rcp(1.0f + e);
}

// register-only f32 -> bf16 bits (no local-array puns -> no scratch)
__device__ __forceinline__ unsigned short bfc(float f) {
  return __builtin_bit_cast(unsigned short, __float2bfloat16(f));
}
__device__ __forceinline__ ushort8 cvt8v(float4 v0, float4 v1) {
  ushort8 o;
  o[0] = bfc(v0.x); o[1] = bfc(v0.y); o[2] = bfc(v0.z); o[3] = bfc(v0.w);
  o[4] = bfc(v1.x); o[5] = bfc(v1.y); o[6] = bfc(v1.z); o[7] = bfc(v1.w);
  return o;
}

// ---------------------------------------------------------------------------
// Prep: build bf16 A=[x|h] (8192x2048), gate-interleaved bf16 W' (4096x2048),
// bsum[4*hh+g]=bx+bh. Unchanged.
// ---------------------------------------------------------------------------
__global__ __launch_bounds__(256) void prep_kernel(
    const float* __restrict__ x, const float* __restrict__ h,
    const float* __restrict__ Wx, const float* __restrict__ Wh,
    const float* __restrict__ bx, const float* __restrict__ bh,
    __hip_bfloat16* __restrict__ Abf, __hip_bfloat16* __restrict__ Wbf,
    float* __restrict__ bsum) {
  const int idx = blockIdx.x * 256 + threadIdx.x;
  const int ATH = (Bsz * Ksz) / 8;  // 2,097,152 threads for A
  if (idx < ATH) {
    const int b = idx >> 8;            // row (2048 elems = 256 chunks/row)
    const int k = (idx & 255) << 3;    // col
    const float* src = (k < Isz) ? (x + (size_t)b * Isz + k)
                                 : (h + (size_t)b * Hsz + (k - Isz));
    const float4 v0 = ((const float4*)src)[0];
    const float4 v1 = ((const float4*)src)[1];
    *(ushort8*)(Abf + (size_t)b * Ksz + k) = cvt8v(v0, v1);
  } else {
    const int t2 = idx - ATH;          // 1,048,576 threads for W'
    const int r = t2 >> 8;             // permuted row 4*hh+g
    const int k = (t2 & 255) << 3;
    const int hh = r >> 2, g = r & 3;
    const float* src = (k < Isz) ? (Wx + (size_t)(g * Hsz + hh) * Isz + k)
                                 : (Wh + (size_t)(g * Hsz + hh) * Hsz + (k - Isz));
    const float4 v0 = ((const float4*)src)[0];
    const float4 v1 = ((const float4*)src)[1];
    *(ushort8*)(Wbf + (size_t)r * Ksz + k) = cvt8v(v0, v1);
  }
  if (idx < Nsz) {
    const int hh = idx >> 2, g = idx & 3;
    bsum[idx] = bx[g * Hsz + hh] + bh[g * Hsz + hh];
  }
}

// ---------------------------------------------------------------------------
// GEMM (A·W'^T) + fused LSTM epilogue — 256², B triple-buffered (160 KB LDS),
// ONE barrier per K-tile, ds_reads pipelined ONE CLUSTER AHEAD.
//
// Round-3 post-mortem: MFMA pipe (49%) + LDS port (46%) ~= 100% of wall ->
// the pipes were SERIALIZED: each cluster's operand reads issued right
// before it, so every cluster began with an exposed lgkmcnt wait (port time
// + ~120cy latency), both waves in lockstep. Fix: step s issues reads for
// cluster s+1, THEN runs cluster s's MFMAs. Read->use distance = one 8-MFMA
// cluster (~155 cyc SIMD pipe) -> LDS latency hidden; compiler emits
// counted lgkmcnt(6) (waits on older reads only). Only R0's 6 reads are
// exposed, once per tile.
//
//   step: R0: B[ks0]x4 + A(0,1|ks0)            [exposed]
//   S0: B[ks1]x4 + A(0,1|ks1); stage A(t+1)h0;  CL(0,ks0)
//   S1: A(2,3|ks0);            stage A(t+1)h1;  CL(0,ks1)
//   S2: A(2,3|ks1);            stage B(t+2)h0;  CL(2,ks0)
//   S3: A(4,5|ks0);            stage B(t+2)h1;  CL(2,ks1)
//   S4: A(4,5|ks1);                             CL(4,ks0)
//   S5: A(6,7|ks0);                             CL(4,ks1)
//   S6: A(6,7|ks1);                             CL(6,ks0)
//   S7:                                         CL(6,ks1)
// a0/a1 ping-pong, all indices compile-time (rule #20).
//
// vmcnt proof (unchanged): per tile VMEM order A(t+1)h0,h1,B(t+2)h0,h1
// (8 ops/thread, SB0-pinned). vmcnt(4) at tile end leaves exactly B(t+2)
// flying; A(t),B(t) resident at tile t via the previous tile's wait + entry
// barrier. Overwrite hazards: A(t+1)->buf last read t-1; B(t+2)->buf last
// read t-1; both dead since tile-t entry barrier. Tail: t=NT-2 vmcnt(0).
//
// LDS XOR swizzle unchanged: qword j of row r at slot j^(r&7) via
// pre-swizzled GLOBAL source (dest linear, rule #21); read side ^(cl&7).
// ---------------------------------------------------------------------------
__global__ __launch_bounds__(512, 2) void lstm_gemm_kernel(
    const __hip_bfloat16* __restrict__ A,   // [8192][2048]
    const __hip_bfloat16* __restrict__ W,   // [4096][2048] gate-interleaved
    const float* __restrict__ bsum,         // [4096] gate-interleaved
    const float* __restrict__ c_prev,       // [8192][1024]
    float* __restrict__ c_out,              // [8192][1024]
    float* __restrict__ h_out) {            // [8192][1024]
  __shared__ ulong2 smem_raw[10240];        // 160 KB exactly
  __hip_bfloat16* const As = (__hip_bfloat16*)smem_raw;   // 2 bufs @ 0, 32 KB
  __hip_bfloat16* const Bs = As + 2 * BUF;                // 3 bufs @ 64 KB+

  const int tid = threadIdx.x;
  const int lane = tid & 63;
  const int wave = tid >> 6;     // 0..7
  const int wm = wave >> 2;      // 0..1 : 128-row half of the 256-row tile
  const int wn = wave & 3;       // 0..3 : 64-col strip of the 256-col tile

  // T1: bijective XCD swizzle (512 blocks, 512 % 8 == 0).
  const int orig = blockIdx.x;
  const int swz = (orig & 7) * 64 + (orig >> 3);
  const int bx = swz & 31;       // 32 row tiles
  const int by = swz >> 5;       // 16 col tiles
  const int row0 = bx * BM;
  const int col0 = by * BN;

  const __hip_bfloat16* const Ag = A + (size_t)row0 * Ksz;
  const __hip_bfloat16* const Wg = W + (size_t)col0 * Ksz;

  // staging: half-tile = 128 rows x 64 cols = 1024 x 16 B chunks; thread
  // stages chunks tid and tid+512 (rows sr, sr+64; 64%8==0 -> same swizzle).
  const int sr = tid >> 3;                       // 0..63
  const int so = ((tid & 7) ^ (sr & 7)) << 3;    // pre-swizzled elem offset

  auto stage = [&](const __hip_bfloat16* gsrc, char* lhalf) {
#pragma unroll
    for (int p = 0; p < 2; ++p)
      async_copy16(gsrc + (size_t)(sr + p * 64) * Ksz,
                   lhalf + (tid + p * 512) * 16);
  };

  const int q = lane >> 4;    // quad
  const int cl = lane & 15;   // row-in-16 within a fragment
  const int phi = cl & 7;     // read-side swizzle phase
  const int swz0 = ((0 + q) ^ phi) << 3;   // ks=0 qword slot -> elem offset
  const int swz1 = ((4 + q) ^ phi) << 3;   // ks=1
  const int aoff0 = (wm * 128 + cl) * BK + swz0;
  const int aoff1 = (wm * 128 + cl) * BK + swz1;
  const int boff0 = (wn * 64 + cl) * BK + swz0;
  const int boff1 = (wn * 64 + cl) * BK + swz1;

  // rotating B buffer pointers: read Bp0 (t%3), write Bp2 ((t+2)%3)
  const __hip_bfloat16* Bp0 = Bs;
  const __hip_bfloat16* Bp1 = Bs + BUF;
  const __hip_bfloat16* Bp2 = Bs + 2 * BUF;

  // ---- prologue: A(0) -> Abuf0; B(0) -> Bbuf0; B(1) -> Bbuf1 (B(1) may fly)
  stage(Ag + so, (char*)As);
  stage(Ag + (size_t)128 * Ksz + so, (char*)As + 16384);
  stage(Wg + so, (char*)Bs);
  stage(Wg + (size_t)128 * Ksz + so, (char*)Bs + 16384);
  __builtin_amdgcn_sched_barrier(0);   // pin VMEM order for vmcnt counting
  stage(Wg + BK + so, (char*)(Bs + BUF));
  stage(Wg + BK + (size_t)128 * Ksz + so, (char*)(Bs + BUF) + 16384);
  __builtin_amdgcn_sched_barrier(0);
  asm volatile("s_waitcnt vmcnt(4)" ::: "memory");  // A(0),B(0) landed
  __builtin_amdgcn_s_barrier();
  __builtin_amdgcn_sched_barrier(0);

  f32x4 acc[8][4] = {};

#define SB0 __builtin_amdgcn_sched_barrier(0);

// read A fragment pair (rows m, m+1), K-half ks, into dst[0..1]
#define LDA(dst, m, ks)                                                    \
  dst[0] = *(const bf16x8*)(Asb + aoff##ks + (m) * (16 * BK));             \
  dst[1] = *(const bf16x8*)(Asb + aoff##ks + ((m) + 1) * (16 * BK));

// read all 4 B fragments of one K-half
#define LDB(ks)                                                            \
  _Pragma("unroll")                                                        \
  for (int n = 0; n < 4; ++n)                                              \
    b[n][ks] = *(const bf16x8*)(Bsb + boff##ks + n * (16 * BK));

// 8-MFMA cluster: rows mi,mi+1 x 4n x one K-half, operands p[0..1]
#define CL(mi, ks, p)                                                      \
  __builtin_amdgcn_s_setprio(1);                                           \
  _Pragma("unroll")                                                        \
  for (int n = 0; n < 4; ++n) {                                            \
    acc[mi][n] = __builtin_amdgcn_mfma_f32_16x16x32_bf16(                  \
        p[0], b[n][ks], acc[mi][n], 0, 0, 0);                              \
    acc[(mi) + 1][n] = __builtin_amdgcn_mfma_f32_16x16x32_bf16(            \
        p[1], b[n][ks], acc[(mi) + 1][n], 0, 0, 0);                        \
  }                                                                        \
  __builtin_amdgcn_s_setprio(0);                                           \
  __builtin_amdgcn_sched_barrier(0);

  for (int t = 0; t < NT; ++t) {
    const __hip_bfloat16* const Asb = As + (t & 1) * BUF;
    const __hip_bfloat16* const Bsb = Bp0;
    char* const nA = (char*)As + ((t + 1) & 1) * 32768;   // (t+1).A dest
    char* const nB = (char*)Bp2;                          // (t+2).B dest
    const int kA = (t + 1) * BK;
    const int kB = (t + 2) * BK;
    const bool doA = (t + 1) < NT;   // uniform
    const bool doB = (t + 2) < NT;   // uniform

    bf16x8 b[4][2];          // B fragments, both K-halves
    bf16x8 a0[2], a1[2];     // ping-pong A fragment pairs (static indices)

    // R0 (exposed once per tile): 6 reads gate the first cluster
    LDB(0) LDA(a0, 0, 0)
    SB0
    // S0: reads for CL(0,ks1) + all B ks1; stage A(t+1)h0; run CL(0,ks0)
    LDB(1) LDA(a1, 0, 1)
    if (doA) stage(Ag + kA + so, nA);
    SB0
    CL(0, 0, a0)
    // S1
    LDA(a0, 2, 0)
    if (doA) stage(Ag + kA + (size_t)128 * Ksz + so, nA + 16384);
    SB0
    CL(0, 1, a1)
    // S2
    LDA(a1, 2, 1)
    if (doB) stage(Wg + kB + so, nB);
    SB0
    CL(2, 0, a0)
    // S3
    LDA(a0, 4, 0)
    if (doB) stage(Wg + kB + (size_t)128 * Ksz + so, nB + 16384);
    SB0
    CL(2, 1, a1)
    // S4..S7
    LDA(a1, 4, 1) SB0 CL(4, 0, a0)
    LDA(a0, 6, 0) SB0 CL(4, 1, a1)
    LDA(a1, 6, 1) SB0 CL(6, 0, a0)
    CL(6, 1, a1)

    // end-of-tile: counted drain; B(t+2) stays flying across the barrier
    if (t < NT - 2) {
      asm volatile("s_waitcnt vmcnt(4)" ::: "memory");
    } else if (t == NT - 2) {
      asm volatile("s_waitcnt vmcnt(0)" ::: "memory");   // drain for tail
    }
    __builtin_amdgcn_s_barrier();
    __builtin_amdgcn_sched_barrier(0);

    // rotate B buffers: new read = old Bp1; new write = old Bp0
    const __hip_bfloat16* const tmp = Bp0;
    Bp0 = Bp1; Bp1 = Bp2; Bp2 = tmp;
  }
#undef LDA
#undef LDB
#undef CL
#undef SB0

  // ---- fused LSTM epilogue (LDS round-trip in the now-dead buffer space) ----
  __syncthreads();
  float* const E = (float*)smem_raw + wave * (16 * 68);   // 8 x 4352 B = 34 KB

  float bj[4];
#pragma unroll
  for (int n = 0; n < 4; ++n)
    bj[n] = bsum[col0 + wn * 64 + n * 16 + cl];

  const int hw = (col0 >> 2) + wn * 16;  // wave's h-window start (16 h values)
  const int r16 = lane >> 2;             // read-phase row 0..15
  const int tt = lane & 3;               // read-phase h-quad 0..3

#pragma unroll
  for (int i = 0; i < 8; ++i) {
    // write phase: lane (q,cl) reg r holds C[q*4+r][n*16+cl] of this 16-row tile
#pragma unroll
    for (int n = 0; n < 4; ++n)
#pragma unroll
      for (int r = 0; r < 4; ++r)
        E[(q * 4 + r) * 68 + n * 16 + cl] = acc[i][n][r] + bj[n];
    __builtin_amdgcn_wave_barrier();  // keep write->read order (wave-private)
    // read phase: lane owns row r16, h = hw + tt*4 + (0..3); gate cols 4h'+g
    const float* Er = E + r16 * 68 + tt * 16;
    const float4 f0 = ((const float4*)Er)[0];  // gates of h+0
    const float4 f1 = ((const float4*)Er)[1];  // gates of h+1
    const float4 f2 = ((const float4*)Er)[2];  // gates of h+2
    const float4 f3 = ((const float4*)Er)[3];  // gates of h+3

    const int row = row0 + wm * 128 + i * 16 + r16;
    const size_t off = (size_t)row * Hsz + hw + tt * 4;
    const float4 cp4 = *(const float4*)(c_prev + off);
    float4 c4, h4;
    {
      const float cn = sigmoid_f(f0.y) * cp4.x + sigmoid_f(f0.x) * tanh_f(f0.w);
      c4.x = cn; h4.x = sigmoid_f(f0.z) * tanh_f(cn);
    }
    {
      const float cn = sigmoid_f(f1.y) * cp4.y + sigmoid_f(f1.x) * tanh_f(f1.w);
      c4.y = cn; h4.y = sigmoid_f(f1.z) * tanh_f(cn);
    }
    {
      const float cn = sigmoid_f(f2.y) * cp4.z + sigmoid_f(f2.x) * tanh_f(f2.w);
      c4.z = cn; h4.z = sigmoid_f(f2.z) * tanh_f(cn);
    }
    {
      const float cn = sigmoid_f(f3.y) * cp4.w + sigmoid_f(f3.x) * tanh_f(f3.w);
      c4.w = cn; h4.w = sigmoid_f(f3.z) * tanh_f(cn);
    }
    *(float4*)(c_out + off) = c4;
    *(float4*)(h_out + off) = h4;
    __builtin_amdgcn_wave_barrier();  // next i reuses E
  }
}

extern "C" void kernel_launch(void* const* d_in, const int* in_sizes, int n_in,
                              void* d_out, int out_size, void* d_ws,
                              size_t ws_size, hipStream_t stream) {
  (void)in_sizes; (void)n_in; (void)out_size; (void)ws_size;
  const float* x  = (const float*)d_in[0];
  const float* cp = (const float*)d_in[1];
  const float* hp = (const float*)d_in[2];
  const float* Wx = (const float*)d_in[3];
  const float* bx = (const float*)d_in[4];
  const float* Wh = (const float*)d_in[5];
  const float* bh = (const float*)d_in[6];

  __hip_bfloat16* Abf = (__hip_bfloat16*)d_ws;            // 32 MB
  __hip_bfloat16* Wbf = Abf + (size_t)Bsz * Ksz;          // 16 MB
  float* bsum = (float*)(Wbf + (size_t)Nsz * Ksz);        // 16 KB

  float* c_out = (float*)d_out;
  float* h_out = c_out + (size_t)Bsz * Hsz;

  const int total_threads = (Bsz * Ksz) / 8 + (Nsz * Ksz) / 8;  // 3,145,728
  prep_kernel<<<total_threads / 256, 256, 0, stream>>>(x, hp, Wx, Wh, bx, bh,
                                                       Abf, Wbf, bsum);
  dim3 grid(Bsz / BM * (Nsz / BN));  // 32 x 16 = 512 blocks (1D, swizzled)
  lstm_gemm_kernel<<<grid, 512, 0, stream>>>(Abf, Wbf, bsum, cp, c_out, h_out);
}